// Round 1
// baseline (506.058 us; speedup 1.0000x reference)
//
#include <hip/hip_runtime.h>

#define NPTS 10000
#define CH 256
#define HH 200
#define WW 400
#define HW 80000

typedef __attribute__((ext_vector_type(8))) short short8;
typedef __attribute__((ext_vector_type(4))) float f32x4;

__device__ __forceinline__ unsigned short f2bf(float f){
    unsigned int u = __float_as_uint(f);
    u += 0x7fff + ((u >> 16) & 1);   // round-to-nearest-even
    return (unsigned short)(u >> 16);
}

__global__ void cast_w_kernel(const float* __restrict__ Wp, unsigned short* __restrict__ Wb){
    int i = blockIdx.x * 256 + threadIdx.x;
    Wb[i] = f2bf(Wp[i]);
}

#define LDSTRIDE 264   // shorts per point row: 256 + 8 pad -> 528B, 16B-aligned rows

__global__ __launch_bounds__(256) void fused_kernel(
    const float* __restrict__ inst,
    const float* __restrict__ anchor,
    const float* __restrict__ bev,
    const unsigned short* __restrict__ Wb,
    const float* __restrict__ bias,
    float* __restrict__ out)
{
    __shared__ unsigned short feat[64 * LDSTRIDE];

    int t = threadIdx.x;

    // ---- Phase 1: sample 64 points x 256 channels into LDS (bf16) ----
    {
        int p  = t & 63;           // point within block (wave lanes span points)
        int cb = t >> 6;           // channel block: this thread does c = cb*64 .. cb*64+63
        int g  = blockIdx.x * 64 + p;
        int b  = g / NPTS;

        float ax = anchor[g*3 + 0];
        float ay = anchor[g*3 + 1];
        // module: grid_x (from ax) is the HEIGHT coord, grid_y (from ay) the WIDTH coord
        float gx_h = (ax + 80.0f) / 200.000001f * 2.0f - 1.0f;
        float gy_w = (ay + 40.0f) / 80.000001f  * 2.0f - 1.0f;
        float ix = (gy_w + 1.0f) * 0.5f * (float)(WW - 1);
        float iy = (gx_h + 1.0f) * 0.5f * (float)(HH - 1);
        float x0f = floorf(ix), y0f = floorf(iy);
        float wx1 = ix - x0f, wx0 = 1.0f - wx1;
        float wy1 = iy - y0f, wy0 = 1.0f - wy1;
        float x1f = x0f + 1.0f, y1f = y0f + 1.0f;
        bool vx0 = (x0f >= 0.0f) && (x0f <= (float)(WW-1));
        bool vx1 = (x1f >= 0.0f) && (x1f <= (float)(WW-1));
        bool vy0 = (y0f >= 0.0f) && (y0f <= (float)(HH-1));
        bool vy1 = (y1f >= 0.0f) && (y1f <= (float)(HH-1));
        int x0 = (int)fminf(fmaxf(x0f, 0.0f), (float)(WW-1));
        int x1 = (int)fminf(fmaxf(x1f, 0.0f), (float)(WW-1));
        int y0 = (int)fminf(fmaxf(y0f, 0.0f), (float)(HH-1));
        int y1 = (int)fminf(fmaxf(y1f, 0.0f), (float)(HH-1));
        float w00 = wx0*wy0 * ((vx0 && vy0) ? 1.0f : 0.0f);
        float w10 = wx1*wy0 * ((vx1 && vy0) ? 1.0f : 0.0f);
        float w01 = wx0*wy1 * ((vx0 && vy1) ? 1.0f : 0.0f);
        float w11 = wx1*wy1 * ((vx1 && vy1) ? 1.0f : 0.0f);
        int c00 = y0*WW + x0;
        int c10 = y0*WW + x1;
        int c01 = y1*WW + x0;
        int c11 = y1*WW + x1;

        const float* pb = bev + ((size_t)b*CH + cb*64) * HW;
        unsigned short* fl = &feat[p * LDSTRIDE + cb*64];
        #pragma unroll 4
        for (int i = 0; i < 64; ++i){
            const float* pc = pb + (size_t)i * HW;
            float v = w00*pc[c00] + w10*pc[c10] + w01*pc[c01] + w11*pc[c11];
            fl[i] = f2bf(v);
        }
    }
    __syncthreads();

    // ---- Phase 2: GEMM  out[64x256] = feat[64x256] * W^T  via mfma 16x16x32 bf16 ----
    int wid  = t >> 6;      // wave id: owns o in [wid*64, wid*64+64)
    int lane = t & 63;
    int lr = lane & 15;
    int lg = lane >> 4;

    f32x4 acc[4][4];
    #pragma unroll
    for (int i=0;i<4;++i)
        #pragma unroll
        for (int j=0;j<4;++j) acc[i][j] = (f32x4){0.f,0.f,0.f,0.f};

    #pragma unroll
    for (int ks = 0; ks < 8; ++ks){
        int cbase = ks*32 + lg*8;
        short8 afr[4], bfr[4];
        #pragma unroll
        for (int mt=0; mt<4; ++mt)
            afr[mt] = *(const short8*)&feat[(mt*16 + lr)*LDSTRIDE + cbase];
        #pragma unroll
        for (int nt=0; nt<4; ++nt)
            bfr[nt] = *(const short8*)&Wb[(size_t)(wid*64 + nt*16 + lr)*CH + cbase];
        #pragma unroll
        for (int mt=0; mt<4; ++mt){
            #pragma unroll
            for (int nt=0; nt<4; ++nt)
                acc[mt][nt] = __builtin_amdgcn_mfma_f32_16x16x32_bf16(afr[mt], bfr[nt], acc[mt][nt], 0, 0, 0);
        }
    }

    // ---- Epilogue: + bias + instance_feature, write f32 ----
    size_t gbase = (size_t)blockIdx.x * 64;
    #pragma unroll
    for (int nt=0; nt<4; ++nt){
        int o = wid*64 + nt*16 + lr;
        float bv = bias[o];
        #pragma unroll
        for (int mt=0; mt<4; ++mt){
            #pragma unroll
            for (int j=0; j<4; ++j){
                int p = mt*16 + lg*4 + j;        // D row = (lane>>4)*4 + reg
                size_t idx = (gbase + p)*CH + o;
                out[idx] = acc[mt][nt][j] + bv + inst[idx];
            }
        }
    }
}

extern "C" void kernel_launch(void* const* d_in, const int* in_sizes, int n_in,
                              void* d_out, int out_size, void* d_ws, size_t ws_size,
                              hipStream_t stream) {
    const float* inst   = (const float*)d_in[0];   // (B,N,C)
    const float* anchor = (const float*)d_in[1];   // (B,N,3)
    // d_in[2] = anchor_embed (unused by the reference output)
    const float* bev    = (const float*)d_in[3];   // (B,C,H,W)
    const float* Wp     = (const float*)d_in[4];   // (C,C) row-major (o,c)
    const float* bias   = (const float*)d_in[5];   // (C,)
    float* out = (float*)d_out;

    unsigned short* Wb = (unsigned short*)d_ws;    // 256*256 bf16 = 128KB

    cast_w_kernel<<<CH*CH/256, 256, 0, stream>>>(Wp, Wb);

    int nblocks = (4*NPTS) / 64;   // 625
    fused_kernel<<<nblocks, 256, 0, stream>>>(inst, anchor, bev, Wb, bias, out);
}